// Round 3
// baseline (149.588 us; speedup 1.0000x reference)
//
#include <hip/hip_runtime.h>

// Problem dims (AdditiveAttention_56865366999388)
#define NB 4
#define NQL 512   // query length
#define ML 512    // key/value length
#define DDIM 256  // DQ == DK == DV
#define HDIM 256  // H

static constexpr float TWO_LOG2E = 2.8853900817779268f; // 2*log2(e)
static constexpr float LOG2E     = 1.4426950408889634f;

// ---------------------------------------------------------------------------
// Kernel 1: projection + exp. NO LDS; depth-4 register software pipeline.
//   EqT[b][h][l] = exp2(TWO_LOG2E * sum_d src[l][d]*W[d][h])  (= e^{2q})
// 64l x 64h tile, 512 thr, 2l x 4h per thread. grid 256 (1D),
// idx&7 = (which,b) -> XCD pinning under %8 round-robin heuristic.
// ---------------------------------------------------------------------------
#define PJX(j, c, Wr)                                   \
    acc[0][0] = fmaf(XA[j].c, Wr[j].x, acc[0][0]);      \
    acc[0][1] = fmaf(XA[j].c, Wr[j].y, acc[0][1]);      \
    acc[0][2] = fmaf(XA[j].c, Wr[j].z, acc[0][2]);      \
    acc[0][3] = fmaf(XA[j].c, Wr[j].w, acc[0][3]);      \
    acc[1][0] = fmaf(XB[j].c, Wr[j].x, acc[1][0]);      \
    acc[1][1] = fmaf(XB[j].c, Wr[j].y, acc[1][1]);      \
    acc[1][2] = fmaf(XB[j].c, Wr[j].z, acc[1][2]);      \
    acc[1][3] = fmaf(XB[j].c, Wr[j].w, acc[1][3]);
#define PJ_STEP(j) { PJX(j, x, W0) PJX(j, y, W1) PJX(j, z, W2) PJX(j, w, W3) }

__global__ __launch_bounds__(512) void proj_kernel(
    const float* __restrict__ q_src, const float* __restrict__ k_src,
    const float* __restrict__ Wq,    const float* __restrict__ Wk,
    float* __restrict__ EqT,         float* __restrict__ EkT)
{
    const int idx   = blockIdx.x;
    const int b     = idx & 3;
    const int which = (idx >> 2) & 1;
    const int lt    = (idx >> 3) & 7;
    const int ht    = idx >> 6;
    const float* __restrict__ src = which ? k_src : q_src;
    const float* __restrict__ W   = which ? Wk : Wq;
    float* __restrict__ outT      = which ? EkT : EqT;

    const int l0 = lt * 64, h0 = ht * 64;
    const int t  = threadIdx.x;
    const int tx = t & 15;   // h group (4 each)
    const int ty = t >> 4;   // l group (2 each), 0..31

    const float* xr0 = &src[(size_t)(b * NQL + l0 + ty * 2) * DDIM];
    const float* xr1 = xr0 + DDIM;
    const float* wc  = &W[h0 + tx * 4];

    float4 XA[4], XB[4], W0[4], W1[4], W2[4], W3[4];
    #pragma unroll
    for (int j = 0; j < 4; ++j) {        // preload dc = 0..3
        XA[j] = *(const float4*)(xr0 + j * 4);
        XB[j] = *(const float4*)(xr1 + j * 4);
        const float* wr = wc + (size_t)(j * 4) * HDIM;
        W0[j] = *(const float4*)(wr);
        W1[j] = *(const float4*)(wr + HDIM);
        W2[j] = *(const float4*)(wr + 2 * HDIM);
        W3[j] = *(const float4*)(wr + 3 * HDIM);
    }
    float acc[2][4] = {};

    for (int g = 0; g < 15; ++g) {
        #pragma unroll
        for (int j = 0; j < 4; ++j) {
            PJ_STEP(j)
            const int dc = 4 * g + j + 4;       // reload set j for dc
            XA[j] = *(const float4*)(xr0 + dc * 4);
            XB[j] = *(const float4*)(xr1 + dc * 4);
            const float* wr = wc + (size_t)(dc * 4) * HDIM;
            W0[j] = *(const float4*)(wr);
            W1[j] = *(const float4*)(wr + HDIM);
            W2[j] = *(const float4*)(wr + 2 * HDIM);
            W3[j] = *(const float4*)(wr + 3 * HDIM);
        }
    }
    #pragma unroll
    for (int j = 0; j < 4; ++j) { PJ_STEP(j) }   // drain dc = 60..63

    #pragma unroll
    for (int j = 0; j < 4; ++j) {
        float2 o;   // e^{2*proj}, stored h-major: [b][h][l]
        o.x = __builtin_amdgcn_exp2f(acc[0][j] * TWO_LOG2E);
        o.y = __builtin_amdgcn_exp2f(acc[1][j] * TWO_LOG2E);
        *(float2*)&outT[(size_t)(b * HDIM + h0 + tx * 4 + j) * NQL + l0 + ty * 2] = o;
    }
}

// ---------------------------------------------------------------------------
// Kernel 2: scores + exp + partial row sums. NO LDS; depth-8 reg pipeline.
//   tanh(q+k) = 1 - 2/(e^{2q}e^{2k}+1);  S = sum_h Wv[h] - 2*sum_h Wv[h]/a,
//   a = fma(Eq,Ek,1). Paired rcp; nw2*r shared by the pair (26 VALU/8 evals).
//   P = exp(S) unnormalized (|S| <= sum|Wv| ~ 13, safe in fp32).
// 32n x 128m tile, 512 thr, 2n x 4m per thread. grid 256 (1D),
// idx&7 = (b, mt&1): per-XCD working set Eq[b]+half Ek[b] = 768KB, L2-fit.
// ---------------------------------------------------------------------------
#define SC_STEP(j, wv)                                       \
    {                                                        \
        swv += (wv);                                         \
        const float nw2 = -2.0f * (wv);                      \
        float a00 = fmaf(QV[j].x, KV[j].x, 1.0f);            \
        float a01 = fmaf(QV[j].x, KV[j].y, 1.0f);            \
        float a02 = fmaf(QV[j].x, KV[j].z, 1.0f);            \
        float a03 = fmaf(QV[j].x, KV[j].w, 1.0f);            \
        float a10 = fmaf(QV[j].y, KV[j].x, 1.0f);            \
        float a11 = fmaf(QV[j].y, KV[j].y, 1.0f);            \
        float a12 = fmaf(QV[j].y, KV[j].z, 1.0f);            \
        float a13 = fmaf(QV[j].y, KV[j].w, 1.0f);            \
        float r0 = __builtin_amdgcn_rcpf(a00 * a01);         \
        float r1 = __builtin_amdgcn_rcpf(a02 * a03);         \
        float r2 = __builtin_amdgcn_rcpf(a10 * a11);         \
        float r3 = __builtin_amdgcn_rcpf(a12 * a13);         \
        float t0 = nw2 * r0, t1 = nw2 * r1;                  \
        float t2 = nw2 * r2, t3 = nw2 * r3;                  \
        acc0[0] = fmaf(t0, a01, acc0[0]);                    \
        acc0[1] = fmaf(t0, a00, acc0[1]);                    \
        acc0[2] = fmaf(t1, a03, acc0[2]);                    \
        acc0[3] = fmaf(t1, a02, acc0[3]);                    \
        acc1[0] = fmaf(t2, a11, acc1[0]);                    \
        acc1[1] = fmaf(t2, a10, acc1[1]);                    \
        acc1[2] = fmaf(t3, a13, acc1[2]);                    \
        acc1[3] = fmaf(t3, a12, acc1[3]);                    \
    }

__global__ __launch_bounds__(512) void scores_kernel(
    const float* __restrict__ EqT, const float* __restrict__ EkT,
    const float* __restrict__ Wv, float* __restrict__ P,
    float* __restrict__ Spart)
{
    const int idx = blockIdx.x;
    const int b   = idx & 3;
    const int mt  = (idx >> 2) & 3;
    const int nt  = idx >> 4;          // 0..15
    const int m0  = mt * 128, n0 = nt * 32;
    const int t   = threadIdx.x;
    const int tx  = t & 31;   // m group (4 each)
    const int ty  = t >> 5;   // n group (2 each), 0..15

    const float* qbase = &EqT[(size_t)b * HDIM * NQL + n0 + ty * 2];
    const float* kbase = &EkT[(size_t)b * HDIM * ML + m0 + tx * 4];

    float2 QV[8];
    float4 KV[8];
    float  WB[8];
    #pragma unroll
    for (int j = 0; j < 8; ++j) {        // preload hh = 0..7
        QV[j] = *(const float2*)(qbase + (size_t)j * NQL);
        KV[j] = *(const float4*)(kbase + (size_t)j * ML);
        WB[j] = Wv[j];
    }

    float acc0[4] = {}, acc1[4] = {};
    float swv = 0.f;

    for (int g = 0; g < 31; ++g) {
        const float* qn = qbase + (size_t)(8 * g + 8) * NQL;
        const float* kn = kbase + (size_t)(8 * g + 8) * ML;
        #pragma unroll
        for (int j = 0; j < 8; ++j) {
            SC_STEP(j, WB[j])
            QV[j] = *(const float2*)(qn + (size_t)j * NQL);  // hh = 8g+j+8
            KV[j] = *(const float4*)(kn + (size_t)j * ML);
            WB[j] = Wv[8 * g + 8 + j];
        }
    }
    #pragma unroll
    for (int j = 0; j < 8; ++j) { SC_STEP(j, WB[j]) }   // drain hh = 248..255

    // epilogue: P = exp(S), partial row sums over this block's 128 m.
    float rs[2];
    {
        float4 p;
        p.x = __builtin_amdgcn_exp2f((swv + acc0[0]) * LOG2E);
        p.y = __builtin_amdgcn_exp2f((swv + acc0[1]) * LOG2E);
        p.z = __builtin_amdgcn_exp2f((swv + acc0[2]) * LOG2E);
        p.w = __builtin_amdgcn_exp2f((swv + acc0[3]) * LOG2E);
        *(float4*)&P[(size_t)(b * NQL + n0 + ty * 2 + 0) * ML + m0 + tx * 4] = p;
        rs[0] = (p.x + p.y) + (p.z + p.w);
    }
    {
        float4 p;
        p.x = __builtin_amdgcn_exp2f((swv + acc1[0]) * LOG2E);
        p.y = __builtin_amdgcn_exp2f((swv + acc1[1]) * LOG2E);
        p.z = __builtin_amdgcn_exp2f((swv + acc1[2]) * LOG2E);
        p.w = __builtin_amdgcn_exp2f((swv + acc1[3]) * LOG2E);
        *(float4*)&P[(size_t)(b * NQL + n0 + ty * 2 + 1) * ML + m0 + tx * 4] = p;
        rs[1] = (p.x + p.y) + (p.z + p.w);
    }
    #pragma unroll
    for (int off = 1; off < 32; off <<= 1) {   // reduce across tx (32 lanes)
        rs[0] += __shfl_xor(rs[0], off);
        rs[1] += __shfl_xor(rs[1], off);
    }
    if (tx == 0) {
        float2 o = {rs[0], rs[1]};
        *(float2*)&Spart[(size_t)(mt * NB + b) * NQL + n0 + ty * 2] = o;
    }
}

// ---------------------------------------------------------------------------
// Kernel 3: out[b][n][v] = (sum_m P[b][n][m] * V[b][m][v]) / rowsum[b][n]
// NO LDS for operands; depth-4 reg pipeline over 4-m chunks.
// 16n x 64v tile, m-split 4 across the block's 4 waves (128 m each),
// 256 thr, 4n x 4v per thread. LDS only for 3->1 epilogue reduce.
// grid 512 (1D): idx = b | vt<<2 | nt<<4  (2 blocks/CU, 8 waves/CU).
// ---------------------------------------------------------------------------
#define AV_ONE(j, i, r, comp)                                        \
    acc[i][0] = fmaf(PS[j][i].comp, VS[j][r].x, acc[i][0]);          \
    acc[i][1] = fmaf(PS[j][i].comp, VS[j][r].y, acc[i][1]);          \
    acc[i][2] = fmaf(PS[j][i].comp, VS[j][r].z, acc[i][2]);          \
    acc[i][3] = fmaf(PS[j][i].comp, VS[j][r].w, acc[i][3]);
#define AV_R(j, r, comp) \
    AV_ONE(j, 0, r, comp) AV_ONE(j, 1, r, comp) AV_ONE(j, 2, r, comp) AV_ONE(j, 3, r, comp)
#define AV_STEP(j) AV_R(j, 0, x) AV_R(j, 1, y) AV_R(j, 2, z) AV_R(j, 3, w)

__global__ __launch_bounds__(256) void av_kernel(
    const float* __restrict__ P, const float* __restrict__ Spart,
    const float* __restrict__ V, float* __restrict__ O)
{
    const int idx = blockIdx.x;
    const int b   = idx & 3;
    const int vt  = (idx >> 2) & 3;
    const int nt  = idx >> 4;          // 0..31
    const int v0  = vt * 64, n0 = nt * 16;
    const int t    = threadIdx.x;
    const int lane = t & 63;
    const int wid  = t >> 6;    // m-quarter selector (4 waves)
    const int tx   = lane & 15; // v group (4 each)
    const int tn   = lane >> 4; // n group (4 rows each)

    __shared__ float sInv[16];
    __shared__ float sRed[3][16][64];   // 12 KB epilogue reduce

    if (t < 16) {   // softmax denominators from scores partials (wave 0)
        float s = 0.f;
        #pragma unroll
        for (int mt = 0; mt < 4; ++mt)
            s += Spart[(size_t)(mt * NB + b) * NQL + n0 + t];
        sInv[t] = 1.0f / s;
    }

    const float* pbase = &P[(size_t)(b * NQL + n0 + tn * 4) * ML + wid * 128];
    const float* vbase = &V[(size_t)(b * ML + wid * 128) * DDIM + v0 + tx * 4];

    float4 PS[4][4], VS[4][4];     // [set][row]; PS row = n, VS row = m
    #pragma unroll
    for (int j = 0; j < 4; ++j) {  // preload mc = 0..3
        #pragma unroll
        for (int r = 0; r < 4; ++r) {
            PS[j][r] = *(const float4*)(pbase + (size_t)r * ML + j * 4);
            VS[j][r] = *(const float4*)(vbase + (size_t)(j * 4 + r) * DDIM);
        }
    }
    float acc[4][4] = {};

    for (int g = 0; g < 7; ++g) {
        #pragma unroll
        for (int j = 0; j < 4; ++j) {
            AV_STEP(j)
            const int mc = 4 * g + j + 4;       // reload set j
            #pragma unroll
            for (int r = 0; r < 4; ++r) {
                PS[j][r] = *(const float4*)(pbase + (size_t)r * ML + mc * 4);
                VS[j][r] = *(const float4*)(vbase + (size_t)(mc * 4 + r) * DDIM);
            }
        }
    }
    #pragma unroll
    for (int j = 0; j < 4; ++j) { AV_STEP(j) }   // drain mc = 28..31

    __syncthreads();
    if (wid != 0) {
        #pragma unroll
        for (int i = 0; i < 4; ++i) {
            float4 r = {acc[i][0], acc[i][1], acc[i][2], acc[i][3]};
            *(float4*)&sRed[wid - 1][tn * 4 + i][tx * 4] = r;
        }
    }
    __syncthreads();
    if (wid == 0) {
        #pragma unroll
        for (int i = 0; i < 4; ++i) {
            float4 r1 = *(const float4*)&sRed[0][tn * 4 + i][tx * 4];
            float4 r2 = *(const float4*)&sRed[1][tn * 4 + i][tx * 4];
            float4 r3 = *(const float4*)&sRed[2][tn * 4 + i][tx * 4];
            const float inv = sInv[tn * 4 + i];
            float4 o;
            o.x = (acc[i][0] + r1.x + r2.x + r3.x) * inv;
            o.y = (acc[i][1] + r1.y + r2.y + r3.y) * inv;
            o.z = (acc[i][2] + r1.z + r2.z + r3.z) * inv;
            o.w = (acc[i][3] + r1.w + r2.w + r3.w) * inv;
            *(float4*)&O[(size_t)(b * NQL + n0 + tn * 4 + i) * DDIM + v0 + tx * 4] = o;
        }
    }
}

// ---------------------------------------------------------------------------
extern "C" void kernel_launch(void* const* d_in, const int* in_sizes, int n_in,
                              void* d_out, int out_size, void* d_ws, size_t ws_size,
                              hipStream_t stream)
{
    const float* query = (const float*)d_in[0]; // (4,512,256)
    const float* key   = (const float*)d_in[1]; // (4,512,256)
    const float* value = (const float*)d_in[2]; // (4,512,256)
    const float* Wq    = (const float*)d_in[3]; // (256,256)
    const float* Wk    = (const float*)d_in[4]; // (256,256)
    const float* Wv    = (const float*)d_in[5]; // (256,)
    float* out = (float*)d_out;                 // (4,512,256)

    // workspace layout (fp32): EqT 2MB | EkT 2MB | P 4MB | Spart 32KB
    float* EqT   = (float*)d_ws;                      // [4][256][512]
    float* EkT   = EqT + (size_t)NB * HDIM * NQL;     // [4][256][512]
    float* P     = EkT + (size_t)NB * HDIM * ML;      // [4][512][512] (= exp(S))
    float* Spart = P + (size_t)NB * NQL * ML;         // [4][4][512] partial row sums

    proj_kernel<<<dim3(256), 512, 0, stream>>>(query, key, Wq, Wk, EqT, EkT);
    scores_kernel<<<dim3(256), 512, 0, stream>>>(EqT, EkT, Wv, P, Spart);
    av_kernel<<<dim3(512), 256, 0, stream>>>(P, Spart, value, out);
}

// Round 4
// 143.565 us; speedup vs baseline: 1.0420x; 1.0420x over previous
//
#include <hip/hip_runtime.h>

// Problem dims (AdditiveAttention_56865366999388)
#define NB 4
#define NQL 512   // query length
#define ML 512    // key/value length
#define DDIM 256  // DQ == DK == DV
#define HDIM 256  // H

static constexpr float TWO_LOG2E = 2.8853900817779268f; // 2*log2(e)
static constexpr float LOG2E     = 1.4426950408889634f;

#define SB() __builtin_amdgcn_sched_barrier(0)

// ---------------------------------------------------------------------------
// Kernel 1: projection + exp. NO LDS; double-buffered register pipeline,
// fenced with sched_barrier(0) so the loads stay hoisted above the compute.
//   EqT[b][h][l] = exp2(TWO_LOG2E * sum_d src[l][d]*W[d][h])  (= e^{2q})
// 64l x 64h tile, 512 thr, 2l x 4h per thread. Chunk = 8 d (12 x b128 loads,
// 64 fma compute). grid 256 (1D), idx&7 = (which,b) for XCD spread.
// ---------------------------------------------------------------------------
#define PJC(xs0, xs1, wv)                              \
    acc[0][0] = fmaf(xs0, (wv).x, acc[0][0]);          \
    acc[0][1] = fmaf(xs0, (wv).y, acc[0][1]);          \
    acc[0][2] = fmaf(xs0, (wv).z, acc[0][2]);          \
    acc[0][3] = fmaf(xs0, (wv).w, acc[0][3]);          \
    acc[1][0] = fmaf(xs1, (wv).x, acc[1][0]);          \
    acc[1][1] = fmaf(xs1, (wv).y, acc[1][1]);          \
    acc[1][2] = fmaf(xs1, (wv).z, acc[1][2]);          \
    acc[1][3] = fmaf(xs1, (wv).w, acc[1][3]);

#define PJ_LOAD(X0, X1, Wr, c)                                         \
    {                                                                  \
        const int d0_ = (c) * 8;                                       \
        X0[0] = *(const float4*)(xr0 + d0_);                           \
        X0[1] = *(const float4*)(xr0 + d0_ + 4);                       \
        X1[0] = *(const float4*)(xr1 + d0_);                           \
        X1[1] = *(const float4*)(xr1 + d0_ + 4);                       \
        _Pragma("unroll")                                              \
        for (int r_ = 0; r_ < 8; ++r_)                                 \
            Wr[r_] = *(const float4*)(wc + (size_t)(d0_ + r_) * HDIM); \
    }

#define PJ_COMP(X0, X1, Wr)                        \
    PJC(X0[0].x, X1[0].x, Wr[0])                   \
    PJC(X0[0].y, X1[0].y, Wr[1])                   \
    PJC(X0[0].z, X1[0].z, Wr[2])                   \
    PJC(X0[0].w, X1[0].w, Wr[3])                   \
    PJC(X0[1].x, X1[1].x, Wr[4])                   \
    PJC(X0[1].y, X1[1].y, Wr[5])                   \
    PJC(X0[1].z, X1[1].z, Wr[6])                   \
    PJC(X0[1].w, X1[1].w, Wr[7])

__global__ __launch_bounds__(512) void proj_kernel(
    const float* __restrict__ q_src, const float* __restrict__ k_src,
    const float* __restrict__ Wq,    const float* __restrict__ Wk,
    float* __restrict__ EqT,         float* __restrict__ EkT)
{
    const int idx   = blockIdx.x;
    const int b     = idx & 3;
    const int which = (idx >> 2) & 1;
    const int lt    = (idx >> 3) & 7;
    const int ht    = idx >> 6;
    const float* __restrict__ src = which ? k_src : q_src;
    const float* __restrict__ W   = which ? Wk : Wq;
    float* __restrict__ outT      = which ? EkT : EqT;

    const int l0 = lt * 64, h0 = ht * 64;
    const int t  = threadIdx.x;
    const int tx = t & 15;   // h group (4 each)
    const int ty = t >> 4;   // l group (2 each), 0..31

    const float* xr0 = &src[(size_t)(b * NQL + l0 + ty * 2) * DDIM];
    const float* xr1 = xr0 + DDIM;
    const float* wc  = &W[h0 + tx * 4];

    float4 XA0[2], XA1[2], WA[8];   // buffer A
    float4 XB0[2], XB1[2], WB[8];   // buffer B
    float acc[2][4] = {};

    // 32 chunks of 8 d. Double-buffered: loads fenced ahead of compute.
    PJ_LOAD(XA0, XA1, WA, 0)
    SB();
    for (int v = 0; v < 15; ++v) {
        PJ_LOAD(XB0, XB1, WB, 2 * v + 1)
        SB();
        PJ_COMP(XA0, XA1, WA)
        SB();
        PJ_LOAD(XA0, XA1, WA, 2 * v + 2)
        SB();
        PJ_COMP(XB0, XB1, WB)
        SB();
    }
    PJ_LOAD(XB0, XB1, WB, 31)
    SB();
    PJ_COMP(XA0, XA1, WA)    // chunk 30
    SB();
    PJ_COMP(XB0, XB1, WB)    // chunk 31

    #pragma unroll
    for (int j = 0; j < 4; ++j) {
        float2 o;   // e^{2*proj}, stored h-major: [b][h][l]
        o.x = __builtin_amdgcn_exp2f(acc[0][j] * TWO_LOG2E);
        o.y = __builtin_amdgcn_exp2f(acc[1][j] * TWO_LOG2E);
        *(float2*)&outT[(size_t)(b * HDIM + h0 + tx * 4 + j) * NQL + l0 + ty * 2] = o;
    }
}

// ---------------------------------------------------------------------------
// Kernel 2: scores + exp + partial row sums. NO LDS; double-buffered
// register pipeline with sched_barrier(0) fences.
//   tanh(q+k) = 1 - 2/(e^{2q}e^{2k}+1);  S = sum_h Wv[h] - 2*sum_h Wv[h]/a,
//   a = fma(Eq,Ek,1). Paired rcp. P = exp(S) unnormalized (|S| <= ~13).
// 32n x 128m tile, 512 thr, 2n x 4m per thread. Chunk = 4 hh
// (4 x {q b64 broadcast, k b128 coalesced, Wv s_load}; ~330 cy compute).
// grid 256 (1D), idx&7 = (b, mt&1): per-XCD set Eq[b]+half Ek[b] L2-fit.
// ---------------------------------------------------------------------------
#define SC_EVAL(Q, K, j, wv)                                 \
    {                                                        \
        swv += (wv);                                         \
        const float nw2 = -2.0f * (wv);                      \
        float a00 = fmaf(Q[j].x, K[j].x, 1.0f);              \
        float a01 = fmaf(Q[j].x, K[j].y, 1.0f);              \
        float a02 = fmaf(Q[j].x, K[j].z, 1.0f);              \
        float a03 = fmaf(Q[j].x, K[j].w, 1.0f);              \
        float a10 = fmaf(Q[j].y, K[j].x, 1.0f);              \
        float a11 = fmaf(Q[j].y, K[j].y, 1.0f);              \
        float a12 = fmaf(Q[j].y, K[j].z, 1.0f);              \
        float a13 = fmaf(Q[j].y, K[j].w, 1.0f);              \
        float r0 = __builtin_amdgcn_rcpf(a00 * a01);         \
        float r1 = __builtin_amdgcn_rcpf(a02 * a03);         \
        float r2 = __builtin_amdgcn_rcpf(a10 * a11);         \
        float r3 = __builtin_amdgcn_rcpf(a12 * a13);         \
        float t0 = nw2 * r0, t1 = nw2 * r1;                  \
        float t2 = nw2 * r2, t3 = nw2 * r3;                  \
        acc0[0] = fmaf(t0, a01, acc0[0]);                    \
        acc0[1] = fmaf(t0, a00, acc0[1]);                    \
        acc0[2] = fmaf(t1, a03, acc0[2]);                    \
        acc0[3] = fmaf(t1, a02, acc0[3]);                    \
        acc1[0] = fmaf(t2, a11, acc1[0]);                    \
        acc1[1] = fmaf(t2, a10, acc1[1]);                    \
        acc1[2] = fmaf(t3, a13, acc1[2]);                    \
        acc1[3] = fmaf(t3, a12, acc1[3]);                    \
    }

#define SC_LOAD(Q, K, Wb, c)                                           \
    {                                                                  \
        const int h0_ = (c) * 4;                                       \
        _Pragma("unroll")                                              \
        for (int j_ = 0; j_ < 4; ++j_) {                               \
            Q[j_]  = *(const float2*)(qbase + (size_t)(h0_ + j_) * NQL); \
            K[j_]  = *(const float4*)(kbase + (size_t)(h0_ + j_) * ML);  \
            Wb[j_] = Wv[h0_ + j_];                                     \
        }                                                              \
    }

#define SC_COMP(Q, K, Wb)                                              \
    { SC_EVAL(Q, K, 0, Wb[0]) SC_EVAL(Q, K, 1, Wb[1])                  \
      SC_EVAL(Q, K, 2, Wb[2]) SC_EVAL(Q, K, 3, Wb[3]) }

__global__ __launch_bounds__(512) void scores_kernel(
    const float* __restrict__ EqT, const float* __restrict__ EkT,
    const float* __restrict__ Wv, float* __restrict__ P,
    float* __restrict__ Spart)
{
    const int idx = blockIdx.x;
    const int b   = idx & 3;
    const int mt  = (idx >> 2) & 3;
    const int nt  = idx >> 4;          // 0..15
    const int m0  = mt * 128, n0 = nt * 32;
    const int t   = threadIdx.x;
    const int tx  = t & 31;   // m group (4 each)
    const int ty  = t >> 5;   // n group (2 each), 0..15

    const float* qbase = &EqT[(size_t)b * HDIM * NQL + n0 + ty * 2];
    const float* kbase = &EkT[(size_t)b * HDIM * ML + m0 + tx * 4];

    float2 QA[4], QB[4];
    float4 KA[4], KB[4];
    float  WA[4], WB[4];
    float acc0[4] = {}, acc1[4] = {};
    float swv = 0.f;

    // 64 chunks of 4 hh. Double-buffered, fenced.
    SC_LOAD(QA, KA, WA, 0)
    SB();
    for (int v = 0; v < 31; ++v) {
        SC_LOAD(QB, KB, WB, 2 * v + 1)
        SB();
        SC_COMP(QA, KA, WA)
        SB();
        SC_LOAD(QA, KA, WA, 2 * v + 2)
        SB();
        SC_COMP(QB, KB, WB)
        SB();
    }
    SC_LOAD(QB, KB, WB, 63)
    SB();
    SC_COMP(QA, KA, WA)      // chunk 62
    SB();
    SC_COMP(QB, KB, WB)      // chunk 63

    // epilogue: P = exp(S), partial row sums over this block's 128 m.
    float rs[2];
    {
        float4 p;
        p.x = __builtin_amdgcn_exp2f((swv + acc0[0]) * LOG2E);
        p.y = __builtin_amdgcn_exp2f((swv + acc0[1]) * LOG2E);
        p.z = __builtin_amdgcn_exp2f((swv + acc0[2]) * LOG2E);
        p.w = __builtin_amdgcn_exp2f((swv + acc0[3]) * LOG2E);
        *(float4*)&P[(size_t)(b * NQL + n0 + ty * 2 + 0) * ML + m0 + tx * 4] = p;
        rs[0] = (p.x + p.y) + (p.z + p.w);
    }
    {
        float4 p;
        p.x = __builtin_amdgcn_exp2f((swv + acc1[0]) * LOG2E);
        p.y = __builtin_amdgcn_exp2f((swv + acc1[1]) * LOG2E);
        p.z = __builtin_amdgcn_exp2f((swv + acc1[2]) * LOG2E);
        p.w = __builtin_amdgcn_exp2f((swv + acc1[3]) * LOG2E);
        *(float4*)&P[(size_t)(b * NQL + n0 + ty * 2 + 1) * ML + m0 + tx * 4] = p;
        rs[1] = (p.x + p.y) + (p.z + p.w);
    }
    #pragma unroll
    for (int off = 1; off < 32; off <<= 1) {   // reduce across the 32 tx lanes
        rs[0] += __shfl_xor(rs[0], off);
        rs[1] += __shfl_xor(rs[1], off);
    }
    if (tx == 0) {
        float2 o = {rs[0], rs[1]};
        *(float2*)&Spart[(size_t)(mt * NB + b) * NQL + n0 + ty * 2] = o;
    }
}

// ---------------------------------------------------------------------------
// Kernel 3: out[b][n][v] = (sum_m P[b][n][m] * V[b][m][v]) / rowsum[b][n]
// NO LDS for operands; double-buffered register pipeline, fenced.
// 16n x 64v tile, m-split 4 across the block's 4 waves (128 m each),
// 256 thr, 4n x 4v per thread. Chunk = 4 m (4 P b128 + 4 V b128, 64 fma).
// LDS only for the 3->1 epilogue reduce. grid 512 (1D), 2 blocks/CU.
// ---------------------------------------------------------------------------
#define AV_ONE(PSb, VSb, i, r, comp)                                 \
    acc[i][0] = fmaf(PSb[i].comp, VSb[r].x, acc[i][0]);              \
    acc[i][1] = fmaf(PSb[i].comp, VSb[r].y, acc[i][1]);              \
    acc[i][2] = fmaf(PSb[i].comp, VSb[r].z, acc[i][2]);              \
    acc[i][3] = fmaf(PSb[i].comp, VSb[r].w, acc[i][3]);
#define AV_RR(PSb, VSb, r, comp)                                     \
    AV_ONE(PSb, VSb, 0, r, comp) AV_ONE(PSb, VSb, 1, r, comp)        \
    AV_ONE(PSb, VSb, 2, r, comp) AV_ONE(PSb, VSb, 3, r, comp)
#define AV_COMP(PSb, VSb)                                            \
    AV_RR(PSb, VSb, 0, x) AV_RR(PSb, VSb, 1, y)                      \
    AV_RR(PSb, VSb, 2, z) AV_RR(PSb, VSb, 3, w)

#define AV_LOAD(PSb, VSb, c)                                              \
    {                                                                     \
        const int mm_ = (c) * 4;                                          \
        _Pragma("unroll")                                                 \
        for (int r_ = 0; r_ < 4; ++r_) {                                  \
            PSb[r_] = *(const float4*)(pbase + (size_t)r_ * ML + mm_);    \
            VSb[r_] = *(const float4*)(vbase + (size_t)(mm_ + r_) * DDIM);\
        }                                                                 \
    }

__global__ __launch_bounds__(256) void av_kernel(
    const float* __restrict__ P, const float* __restrict__ Spart,
    const float* __restrict__ V, float* __restrict__ O)
{
    const int idx = blockIdx.x;
    const int b   = idx & 3;
    const int vt  = (idx >> 2) & 3;
    const int nt  = idx >> 4;          // 0..31
    const int v0  = vt * 64, n0 = nt * 16;
    const int t    = threadIdx.x;
    const int lane = t & 63;
    const int wid  = t >> 6;    // m-quarter selector (4 waves)
    const int tx   = lane & 15; // v group (4 each)
    const int tn   = lane >> 4; // n group (4 rows each)

    __shared__ float sInv[16];
    __shared__ float sRed[3][16][64];   // 12 KB epilogue reduce

    if (t < 16) {   // softmax denominators from scores partials (wave 0)
        float s = 0.f;
        #pragma unroll
        for (int mt = 0; mt < 4; ++mt)
            s += Spart[(size_t)(mt * NB + b) * NQL + n0 + t];
        sInv[t] = 1.0f / s;
    }

    const float* pbase = &P[(size_t)(b * NQL + n0 + tn * 4) * ML + wid * 128];
    const float* vbase = &V[(size_t)(b * ML + wid * 128) * DDIM + v0 + tx * 4];

    float4 PA[4], VA[4];     // buffer A: [row]; P row = n, V row = m
    float4 PB[4], VB[4];     // buffer B
    float acc[4][4] = {};

    // 32 chunks of 4 m. Double-buffered, fenced.
    AV_LOAD(PA, VA, 0)
    SB();
    for (int v = 0; v < 15; ++v) {
        AV_LOAD(PB, VB, 2 * v + 1)
        SB();
        AV_COMP(PA, VA)
        SB();
        AV_LOAD(PA, VA, 2 * v + 2)
        SB();
        AV_COMP(PB, VB)
        SB();
    }
    AV_LOAD(PB, VB, 31)
    SB();
    AV_COMP(PA, VA)          // chunk 30
    SB();
    AV_COMP(PB, VB)          // chunk 31

    __syncthreads();
    if (wid != 0) {
        #pragma unroll
        for (int i = 0; i < 4; ++i) {
            float4 r = {acc[i][0], acc[i][1], acc[i][2], acc[i][3]};
            *(float4*)&sRed[wid - 1][tn * 4 + i][tx * 4] = r;
        }
    }
    __syncthreads();
    if (wid == 0) {
        #pragma unroll
        for (int i = 0; i < 4; ++i) {
            float4 r1 = *(const float4*)&sRed[0][tn * 4 + i][tx * 4];
            float4 r2 = *(const float4*)&sRed[1][tn * 4 + i][tx * 4];
            float4 r3 = *(const float4*)&sRed[2][tn * 4 + i][tx * 4];
            const float inv = sInv[tn * 4 + i];
            float4 o;
            o.x = (acc[i][0] + r1.x + r2.x + r3.x) * inv;
            o.y = (acc[i][1] + r1.y + r2.y + r3.y) * inv;
            o.z = (acc[i][2] + r1.z + r2.z + r3.z) * inv;
            o.w = (acc[i][3] + r1.w + r2.w + r3.w) * inv;
            *(float4*)&O[(size_t)(b * NQL + n0 + tn * 4 + i) * DDIM + v0 + tx * 4] = o;
        }
    }
}

// ---------------------------------------------------------------------------
extern "C" void kernel_launch(void* const* d_in, const int* in_sizes, int n_in,
                              void* d_out, int out_size, void* d_ws, size_t ws_size,
                              hipStream_t stream)
{
    const float* query = (const float*)d_in[0]; // (4,512,256)
    const float* key   = (const float*)d_in[1]; // (4,512,256)
    const float* value = (const float*)d_in[2]; // (4,512,256)
    const float* Wq    = (const float*)d_in[3]; // (256,256)
    const float* Wk    = (const float*)d_in[4]; // (256,256)
    const float* Wv    = (const float*)d_in[5]; // (256,)
    float* out = (float*)d_out;                 // (4,512,256)

    // workspace layout (fp32): EqT 2MB | EkT 2MB | P 4MB | Spart 32KB
    float* EqT   = (float*)d_ws;                      // [4][256][512]
    float* EkT   = EqT + (size_t)NB * HDIM * NQL;     // [4][256][512]
    float* P     = EkT + (size_t)NB * HDIM * ML;      // [4][512][512] (= exp(S))
    float* Spart = P + (size_t)NB * NQL * ML;         // [4][4][512] partial row sums

    proj_kernel<<<dim3(256), 512, 0, stream>>>(query, key, Wq, Wk, EqT, EkT);
    scores_kernel<<<dim3(256), 512, 0, stream>>>(EqT, EkT, Wv, P, Spart);
    av_kernel<<<dim3(512), 256, 0, stream>>>(P, Spart, value, out);
}

// Round 5
// 142.943 us; speedup vs baseline: 1.0465x; 1.0043x over previous
//
#include <hip/hip_runtime.h>

// Problem dims (AdditiveAttention_56865366999388)
#define NB 4
#define NQL 512   // query length
#define ML 512    // key/value length
#define DDIM 256  // DQ == DK == DV
#define HDIM 256  // H

static constexpr float TWO_LOG2E = 2.8853900817779268f; // 2*log2(e)
static constexpr float LOG2E     = 1.4426950408889634f;

#define SB() __builtin_amdgcn_sched_barrier(0)

// ---------------------------------------------------------------------------
// Kernel 1: projection + exp. All-global (no LDS): W rows L1/L2-hot, X rows
// broadcast across tx. 4l x 4h per thread, 64l x 64h per 256-thr block.
// SB-fenced double-buffered register pipeline, chunk = 4 d (8 x b128 loads,
// 64 fma). grid 256 (1D): idx = b | which<<2 | lt<<3 | ht<<6.
// ---------------------------------------------------------------------------
#define PJ_LOAD(Xr, Wr, c)                                          \
    {                                                               \
        const int d_ = (c) * 4;                                     \
        Xr[0] = *(const float4*)(xr0 + d_);                         \
        Xr[1] = *(const float4*)(xr1 + d_);                         \
        Xr[2] = *(const float4*)(xr2 + d_);                         \
        Xr[3] = *(const float4*)(xr3 + d_);                         \
        Wr[0] = *(const float4*)(wc + (size_t)(d_ + 0) * HDIM);     \
        Wr[1] = *(const float4*)(wc + (size_t)(d_ + 1) * HDIM);     \
        Wr[2] = *(const float4*)(wc + (size_t)(d_ + 2) * HDIM);     \
        Wr[3] = *(const float4*)(wc + (size_t)(d_ + 3) * HDIM);     \
    }

#define PJ_FMA(Xr, Wr, i, comp, r)                                  \
    acc[i][0] = fmaf(Xr[i].comp, Wr[r].x, acc[i][0]);               \
    acc[i][1] = fmaf(Xr[i].comp, Wr[r].y, acc[i][1]);               \
    acc[i][2] = fmaf(Xr[i].comp, Wr[r].z, acc[i][2]);               \
    acc[i][3] = fmaf(Xr[i].comp, Wr[r].w, acc[i][3]);

#define PJ_ROW(Xr, Wr, i)                                           \
    PJ_FMA(Xr, Wr, i, x, 0) PJ_FMA(Xr, Wr, i, y, 1)                 \
    PJ_FMA(Xr, Wr, i, z, 2) PJ_FMA(Xr, Wr, i, w, 3)

#define PJ_COMP(Xr, Wr)                                             \
    PJ_ROW(Xr, Wr, 0) PJ_ROW(Xr, Wr, 1)                             \
    PJ_ROW(Xr, Wr, 2) PJ_ROW(Xr, Wr, 3)

__global__ __launch_bounds__(256) void proj_kernel(
    const float* __restrict__ q_src, const float* __restrict__ k_src,
    const float* __restrict__ Wq,    const float* __restrict__ Wk,
    float* __restrict__ EqT,         float* __restrict__ EkT)
{
    const int idx   = blockIdx.x;
    const int b     = idx & 3;
    const int which = (idx >> 2) & 1;
    const int lt    = (idx >> 3) & 7;
    const int ht    = idx >> 6;
    const float* __restrict__ src = which ? k_src : q_src;
    const float* __restrict__ W   = which ? Wk : Wq;
    float* __restrict__ outT      = which ? EkT : EqT;

    const int l0 = lt * 64, h0 = ht * 64;
    const int t  = threadIdx.x;
    const int tx = t & 15;   // h group (4 each)
    const int ty = t >> 4;   // l group (4 each), 0..15

    const float* xr0 = &src[(size_t)(b * NQL + l0 + ty * 4) * DDIM];
    const float* xr1 = xr0 + DDIM;
    const float* xr2 = xr0 + 2 * DDIM;
    const float* xr3 = xr0 + 3 * DDIM;
    const float* wc  = &W[h0 + tx * 4];

    float4 XA[4], WA[4], XB[4], WB[4];
    float acc[4][4] = {};

    // 64 chunks of 4 d, double-buffered + fenced.
    PJ_LOAD(XA, WA, 0)
    SB();
    for (int v = 0; v < 31; ++v) {
        PJ_LOAD(XB, WB, 2 * v + 1)
        SB();
        PJ_COMP(XA, WA)
        SB();
        PJ_LOAD(XA, WA, 2 * v + 2)
        SB();
        PJ_COMP(XB, WB)
        SB();
    }
    PJ_LOAD(XB, WB, 63)
    SB();
    PJ_COMP(XA, WA)      // chunk 62
    SB();
    PJ_COMP(XB, WB)      // chunk 63

    #pragma unroll
    for (int j = 0; j < 4; ++j) {
        float4 o;   // e^{2*proj}, stored h-major: [b][h][l], 4 l contiguous
        o.x = __builtin_amdgcn_exp2f(acc[0][j] * TWO_LOG2E);
        o.y = __builtin_amdgcn_exp2f(acc[1][j] * TWO_LOG2E);
        o.z = __builtin_amdgcn_exp2f(acc[2][j] * TWO_LOG2E);
        o.w = __builtin_amdgcn_exp2f(acc[3][j] * TWO_LOG2E);
        *(float4*)&outT[(size_t)(b * HDIM + h0 + tx * 4 + j) * NQL + l0 + ty * 4] = o;
    }
}

// ---------------------------------------------------------------------------
// Kernel 2: scores + exp + partial row sums. LDS double-buffered staging
// (cuts L2 k-traffic 16x), 4n x 2m register tile (VALU-bound: 19 LDS-cy vs
// 80 compute-cy per hh per wave).
//   tanh(q+k) = 1 - 2/(e^{2q}e^{2k}+1);  S = sum_h Wv[h] - 2*sum_h Wv[h]/a,
//   a = fma(Eq,Ek,1). rcp paired across n. P = exp(S) unnorm (|S| <= ~13).
// 64n x 32m tile, 256 thr. grid 512 (1D): idx = b | mt<<2 | nt<<6
//   -> idx&7 = (b, mt&1): per-XCD working set Eq[b]+half Ek[b] L2-fit.
// 2 blocks/CU, 8 waves/CU: barrier drains overlap across blocks.
// ---------------------------------------------------------------------------
__global__ __launch_bounds__(256) void scores_kernel(
    const float* __restrict__ EqT, const float* __restrict__ EkT,
    const float* __restrict__ Wv, float* __restrict__ P,
    float* __restrict__ Spart)
{
    const int idx = blockIdx.x;
    const int b   = idx & 3;
    const int mt  = (idx >> 2) & 15;
    const int nt  = idx >> 6;          // 0..7
    const int m0  = mt * 32, n0 = nt * 64;
    const int t   = threadIdx.x;
    const int tx  = t & 15;   // m pair (2 each)
    const int ty  = t >> 4;   // n quad (4 each), 0..15

    __shared__ float sQ[2][32][68];   // [hh][nn] 32h x 64n (+pad)
    __shared__ float sK[2][32][36];   // [hh][mm] 32h x 32m (+pad)

    const int rq = t >> 3, cq = t & 7;   // q stage: 32 rows x 8 grps(8 n)
    const int rk = t >> 3, ck = t & 7;   // k stage: 32 rows x 8 grps(4 m)

    const float* qbase = &EqT[(size_t)b * HDIM * NQL + n0];
    const float* kbase = &EkT[(size_t)b * HDIM * ML + m0];

    // preload chunk 0 into staging regs
    float4 q1 = *(const float4*)(qbase + (size_t)rq * NQL + cq * 8);
    float4 q2 = *(const float4*)(qbase + (size_t)rq * NQL + cq * 8 + 4);
    float4 kv = *(const float4*)(kbase + (size_t)rk * ML + ck * 4);

    float acc[4][2] = {};
    float swv = 0.f;
    int cur = 0;

    for (int c = 0; c < 8; ++c) {   // 8 chunks of 32 hh
        *(float4*)&sQ[cur][rq][cq * 8]     = q1;
        *(float4*)&sQ[cur][rq][cq * 8 + 4] = q2;
        *(float4*)&sK[cur][rk][ck * 4]     = kv;
        __syncthreads();
        if (c < 7) {   // prefetch next chunk; latency hides under compute
            const float* qn = qbase + (size_t)((c + 1) * 32 + rq) * NQL;
            q1 = *(const float4*)(qn + cq * 8);
            q2 = *(const float4*)(qn + cq * 8 + 4);
            kv = *(const float4*)(kbase + (size_t)((c + 1) * 32 + rk) * ML + ck * 4);
        }
        const float* wvp = Wv + c * 32;    // uniform -> s_load
        #pragma unroll 8
        for (int hh = 0; hh < 32; ++hh) {
            float4 q4 = *(const float4*)&sQ[cur][hh][ty * 4];
            float2 k2 = *(const float2*)&sK[cur][hh][tx * 2];
            const float wv = wvp[hh];
            swv += wv;
            const float nw2 = -2.0f * wv;
            {   // m = k2.x ; rcp paired across n
                float a0 = fmaf(q4.x, k2.x, 1.0f);
                float a1 = fmaf(q4.y, k2.x, 1.0f);
                float a2 = fmaf(q4.z, k2.x, 1.0f);
                float a3 = fmaf(q4.w, k2.x, 1.0f);
                float r01 = __builtin_amdgcn_rcpf(a0 * a1);
                float r23 = __builtin_amdgcn_rcpf(a2 * a3);
                float t01 = nw2 * r01, t23 = nw2 * r23;
                acc[0][0] = fmaf(t01, a1, acc[0][0]);
                acc[1][0] = fmaf(t01, a0, acc[1][0]);
                acc[2][0] = fmaf(t23, a3, acc[2][0]);
                acc[3][0] = fmaf(t23, a2, acc[3][0]);
            }
            {   // m = k2.y
                float a0 = fmaf(q4.x, k2.y, 1.0f);
                float a1 = fmaf(q4.y, k2.y, 1.0f);
                float a2 = fmaf(q4.z, k2.y, 1.0f);
                float a3 = fmaf(q4.w, k2.y, 1.0f);
                float r01 = __builtin_amdgcn_rcpf(a0 * a1);
                float r23 = __builtin_amdgcn_rcpf(a2 * a3);
                float t01 = nw2 * r01, t23 = nw2 * r23;
                acc[0][1] = fmaf(t01, a1, acc[0][1]);
                acc[1][1] = fmaf(t01, a0, acc[1][1]);
                acc[2][1] = fmaf(t23, a3, acc[2][1]);
                acc[3][1] = fmaf(t23, a2, acc[3][1]);
            }
        }
        cur ^= 1;
    }

    // epilogue: P = exp(S) unnormalized, partial row sums over this block's 32 m
    float rs[4];
    #pragma unroll
    for (int i = 0; i < 4; ++i) {
        float2 p;
        p.x = __builtin_amdgcn_exp2f((swv + acc[i][0]) * LOG2E);
        p.y = __builtin_amdgcn_exp2f((swv + acc[i][1]) * LOG2E);
        *(float2*)&P[(size_t)(b * NQL + n0 + ty * 4 + i) * ML + m0 + tx * 2] = p;
        rs[i] = p.x + p.y;
    }
    #pragma unroll
    for (int off = 1; off < 16; off <<= 1) {   // reduce over the 16 tx lanes
        #pragma unroll
        for (int i = 0; i < 4; ++i) rs[i] += __shfl_xor(rs[i], off);
    }
    if (tx == 0) {
        #pragma unroll
        for (int i = 0; i < 4; ++i)
            Spart[(size_t)(mt * NB + b) * NQL + n0 + ty * 4 + i] = rs[i];
    }
}

// ---------------------------------------------------------------------------
// Kernel 3: out[b][n][v] = (sum_m P[b][n][m] * V[b][m][v]) / rowsum[b][n]
// NO LDS for operands; double-buffered register pipeline, fenced.
// 16n x 64v tile, m-split 4 across the block's 4 waves (128 m each),
// 256 thr, 4n x 4v per thread. Chunk = 4 m (4 P b128 + 4 V b128, 64 fma).
// LDS only for the 3->1 epilogue reduce. grid 512 (1D), 2 blocks/CU.
// ---------------------------------------------------------------------------
#define AV_ONE(PSb, VSb, i, r, comp)                                 \
    acc[i][0] = fmaf(PSb[i].comp, VSb[r].x, acc[i][0]);              \
    acc[i][1] = fmaf(PSb[i].comp, VSb[r].y, acc[i][1]);              \
    acc[i][2] = fmaf(PSb[i].comp, VSb[r].z, acc[i][2]);              \
    acc[i][3] = fmaf(PSb[i].comp, VSb[r].w, acc[i][3]);
#define AV_RR(PSb, VSb, r, comp)                                     \
    AV_ONE(PSb, VSb, 0, r, comp) AV_ONE(PSb, VSb, 1, r, comp)        \
    AV_ONE(PSb, VSb, 2, r, comp) AV_ONE(PSb, VSb, 3, r, comp)
#define AV_COMP(PSb, VSb)                                            \
    AV_RR(PSb, VSb, 0, x) AV_RR(PSb, VSb, 1, y)                      \
    AV_RR(PSb, VSb, 2, z) AV_RR(PSb, VSb, 3, w)

#define AV_LOAD(PSb, VSb, c)                                              \
    {                                                                     \
        const int mm_ = (c) * 4;                                          \
        _Pragma("unroll")                                                 \
        for (int r_ = 0; r_ < 4; ++r_) {                                  \
            PSb[r_] = *(const float4*)(pbase + (size_t)r_ * ML + mm_);    \
            VSb[r_] = *(const float4*)(vbase + (size_t)(mm_ + r_) * DDIM);\
        }                                                                 \
    }

__global__ __launch_bounds__(256) void av_kernel(
    const float* __restrict__ P, const float* __restrict__ Spart,
    const float* __restrict__ V, float* __restrict__ O)
{
    const int idx = blockIdx.x;
    const int b   = idx & 3;
    const int vt  = (idx >> 2) & 3;
    const int nt  = idx >> 4;          // 0..31
    const int v0  = vt * 64, n0 = nt * 16;
    const int t    = threadIdx.x;
    const int lane = t & 63;
    const int wid  = t >> 6;    // m-quarter selector (4 waves)
    const int tx   = lane & 15; // v group (4 each)
    const int tn   = lane >> 4; // n group (4 rows each)

    __shared__ float sInv[16];
    __shared__ float sRed[3][16][64];   // 12 KB epilogue reduce

    if (t < 16) {   // softmax denominators from the 16 scores partials
        float s = 0.f;
        #pragma unroll
        for (int mt = 0; mt < 16; ++mt)
            s += Spart[(size_t)(mt * NB + b) * NQL + n0 + t];
        sInv[t] = 1.0f / s;
    }

    const float* pbase = &P[(size_t)(b * NQL + n0 + tn * 4) * ML + wid * 128];
    const float* vbase = &V[(size_t)(b * ML + wid * 128) * DDIM + v0 + tx * 4];

    float4 PA[4], VA[4];     // buffer A: [row]; P row = n, V row = m
    float4 PB[4], VB[4];     // buffer B
    float acc[4][4] = {};

    // 32 chunks of 4 m. Double-buffered, fenced.
    AV_LOAD(PA, VA, 0)
    SB();
    for (int v = 0; v < 15; ++v) {
        AV_LOAD(PB, VB, 2 * v + 1)
        SB();
        AV_COMP(PA, VA)
        SB();
        AV_LOAD(PA, VA, 2 * v + 2)
        SB();
        AV_COMP(PB, VB)
        SB();
    }
    AV_LOAD(PB, VB, 31)
    SB();
    AV_COMP(PA, VA)          // chunk 30
    SB();
    AV_COMP(PB, VB)          // chunk 31

    __syncthreads();
    if (wid != 0) {
        #pragma unroll
        for (int i = 0; i < 4; ++i) {
            float4 r = {acc[i][0], acc[i][1], acc[i][2], acc[i][3]};
            *(float4*)&sRed[wid - 1][tn * 4 + i][tx * 4] = r;
        }
    }
    __syncthreads();
    if (wid == 0) {
        #pragma unroll
        for (int i = 0; i < 4; ++i) {
            float4 r1 = *(const float4*)&sRed[0][tn * 4 + i][tx * 4];
            float4 r2 = *(const float4*)&sRed[1][tn * 4 + i][tx * 4];
            float4 r3 = *(const float4*)&sRed[2][tn * 4 + i][tx * 4];
            const float inv = sInv[tn * 4 + i];
            float4 o;
            o.x = (acc[i][0] + r1.x + r2.x + r3.x) * inv;
            o.y = (acc[i][1] + r1.y + r2.y + r3.y) * inv;
            o.z = (acc[i][2] + r1.z + r2.z + r3.z) * inv;
            o.w = (acc[i][3] + r1.w + r2.w + r3.w) * inv;
            *(float4*)&O[(size_t)(b * NQL + n0 + tn * 4 + i) * DDIM + v0 + tx * 4] = o;
        }
    }
}

// ---------------------------------------------------------------------------
extern "C" void kernel_launch(void* const* d_in, const int* in_sizes, int n_in,
                              void* d_out, int out_size, void* d_ws, size_t ws_size,
                              hipStream_t stream)
{
    const float* query = (const float*)d_in[0]; // (4,512,256)
    const float* key   = (const float*)d_in[1]; // (4,512,256)
    const float* value = (const float*)d_in[2]; // (4,512,256)
    const float* Wq    = (const float*)d_in[3]; // (256,256)
    const float* Wk    = (const float*)d_in[4]; // (256,256)
    const float* Wv    = (const float*)d_in[5]; // (256,)
    float* out = (float*)d_out;                 // (4,512,256)

    // workspace layout (fp32): EqT 2MB | EkT 2MB | P 4MB | Spart 128KB
    float* EqT   = (float*)d_ws;                      // [4][256][512]
    float* EkT   = EqT + (size_t)NB * HDIM * NQL;     // [4][256][512]
    float* P     = EkT + (size_t)NB * HDIM * ML;      // [4][512][512] (= exp(S))
    float* Spart = P + (size_t)NB * NQL * ML;         // [16][4][512] partial row sums

    proj_kernel<<<dim3(256), 256, 0, stream>>>(query, key, Wq, Wk, EqT, EkT);
    scores_kernel<<<dim3(512), 256, 0, stream>>>(EqT, EkT, Wv, P, Spart);
    av_kernel<<<dim3(512), 256, 0, stream>>>(P, Spart, value, out);
}

// Round 6
// 136.804 us; speedup vs baseline: 1.0935x; 1.0449x over previous
//
#include <hip/hip_runtime.h>

// Problem dims (AdditiveAttention_56865366999388)
#define NB 4
#define NQL 512   // query length
#define ML 512    // key/value length
#define DDIM 256  // DQ == DK == DV
#define HDIM 256  // H

static constexpr float TWO_LOG2E = 2.8853900817779268f; // 2*log2(e)
static constexpr float LOG2E     = 1.4426950408889634f;

#define SB() __builtin_amdgcn_sched_barrier(0)

// ---------------------------------------------------------------------------
// Kernel 1: projection + exp. All-global (no LDS): W rows L1/L2-hot, X rows
// broadcast across tx. 4l x 4h per thread, 64l x 64h per 256-thr block.
// SB-fenced double-buffered register pipeline, chunk = 4 d (8 x b128 loads,
// 64 fma). grid 256 (1D): idx = b | which<<2 | lt<<3 | ht<<6.
// ---------------------------------------------------------------------------
#define PJ_LOAD(Xr, Wr, c)                                          \
    {                                                               \
        const int d_ = (c) * 4;                                     \
        Xr[0] = *(const float4*)(xr0 + d_);                         \
        Xr[1] = *(const float4*)(xr1 + d_);                         \
        Xr[2] = *(const float4*)(xr2 + d_);                         \
        Xr[3] = *(const float4*)(xr3 + d_);                         \
        Wr[0] = *(const float4*)(wc + (size_t)(d_ + 0) * HDIM);     \
        Wr[1] = *(const float4*)(wc + (size_t)(d_ + 1) * HDIM);     \
        Wr[2] = *(const float4*)(wc + (size_t)(d_ + 2) * HDIM);     \
        Wr[3] = *(const float4*)(wc + (size_t)(d_ + 3) * HDIM);     \
    }

#define PJ_FMA(Xr, Wr, i, comp, r)                                  \
    acc[i][0] = fmaf(Xr[i].comp, Wr[r].x, acc[i][0]);               \
    acc[i][1] = fmaf(Xr[i].comp, Wr[r].y, acc[i][1]);               \
    acc[i][2] = fmaf(Xr[i].comp, Wr[r].z, acc[i][2]);               \
    acc[i][3] = fmaf(Xr[i].comp, Wr[r].w, acc[i][3]);

#define PJ_ROW(Xr, Wr, i)                                           \
    PJ_FMA(Xr, Wr, i, x, 0) PJ_FMA(Xr, Wr, i, y, 1)                 \
    PJ_FMA(Xr, Wr, i, z, 2) PJ_FMA(Xr, Wr, i, w, 3)

#define PJ_COMP(Xr, Wr)                                             \
    PJ_ROW(Xr, Wr, 0) PJ_ROW(Xr, Wr, 1)                             \
    PJ_ROW(Xr, Wr, 2) PJ_ROW(Xr, Wr, 3)

__global__ __launch_bounds__(256) void proj_kernel(
    const float* __restrict__ q_src, const float* __restrict__ k_src,
    const float* __restrict__ Wq,    const float* __restrict__ Wk,
    float* __restrict__ EqT,         float* __restrict__ EkT)
{
    const int idx   = blockIdx.x;
    const int b     = idx & 3;
    const int which = (idx >> 2) & 1;
    const int lt    = (idx >> 3) & 7;
    const int ht    = idx >> 6;
    const float* __restrict__ src = which ? k_src : q_src;
    const float* __restrict__ W   = which ? Wk : Wq;
    float* __restrict__ outT      = which ? EkT : EqT;

    const int l0 = lt * 64, h0 = ht * 64;
    const int t  = threadIdx.x;
    const int tx = t & 15;   // h group (4 each)
    const int ty = t >> 4;   // l group (4 each), 0..15

    const float* xr0 = &src[(size_t)(b * NQL + l0 + ty * 4) * DDIM];
    const float* xr1 = xr0 + DDIM;
    const float* xr2 = xr0 + 2 * DDIM;
    const float* xr3 = xr0 + 3 * DDIM;
    const float* wc  = &W[h0 + tx * 4];

    float4 XA[4], WA[4], XB[4], WB[4];
    float acc[4][4] = {};

    // 64 chunks of 4 d, double-buffered + fenced.
    PJ_LOAD(XA, WA, 0)
    SB();
    for (int v = 0; v < 31; ++v) {
        PJ_LOAD(XB, WB, 2 * v + 1)
        SB();
        PJ_COMP(XA, WA)
        SB();
        PJ_LOAD(XA, WA, 2 * v + 2)
        SB();
        PJ_COMP(XB, WB)
        SB();
    }
    PJ_LOAD(XB, WB, 63)
    SB();
    PJ_COMP(XA, WA)      // chunk 62
    SB();
    PJ_COMP(XB, WB)      // chunk 63

    #pragma unroll
    for (int j = 0; j < 4; ++j) {
        float4 o;   // e^{2*proj}, stored h-major: [b][h][l], 4 l contiguous
        o.x = __builtin_amdgcn_exp2f(acc[0][j] * TWO_LOG2E);
        o.y = __builtin_amdgcn_exp2f(acc[1][j] * TWO_LOG2E);
        o.z = __builtin_amdgcn_exp2f(acc[2][j] * TWO_LOG2E);
        o.w = __builtin_amdgcn_exp2f(acc[3][j] * TWO_LOG2E);
        *(float4*)&outT[(size_t)(b * HDIM + h0 + tx * 4 + j) * NQL + l0 + ty * 4] = o;
    }
}

// ---------------------------------------------------------------------------
// Kernel 2: scores + exp + partial row sums.
// KEY CHANGE vs r5: per-thread tile 4n x 4m (16 evals/hh) -> LDS cost
// 1.5 cy/eval (2 x ds_read_b128 per 16 evals) vs VALU ~6.25 cy/eval:
// VALU-bound at 8 waves/CU (LDS/CU 192 cy < VALU/SIMD 200 cy per hh).
// 512 thr = 2 wave-groups of 4; group g sums h in [128g, 128g+128);
// partials combined via LDS in the epilogue (h-split keeps 2 waves/SIMD
// with the 256-thread 64n x 64m tile).
//   tanh(q+k) = 1 - 2/(e^{2q}e^{2k}+1);  S = sum_h Wv[h] - 2*sum_h Wv[h]/a,
//   a = fma(Eq,Ek,1). rcp paired across n. P = exp(S) unnorm (|S| <= ~13).
// 64n x 64m tile, grid 256 (1D): idx = b | mt<<2 | nt<<5; idx&7 = (b,mt&1)
// pins per-XCD working set Eq[b] 512KB + half Ek[b] 256KB (L2-fit).
// ---------------------------------------------------------------------------
#define SC_M(jm, km)                                         \
    {                                                        \
        float a0 = fmaf(q4.x, km, 1.0f);                     \
        float a1 = fmaf(q4.y, km, 1.0f);                     \
        float a2 = fmaf(q4.z, km, 1.0f);                     \
        float a3 = fmaf(q4.w, km, 1.0f);                     \
        float r01 = __builtin_amdgcn_rcpf(a0 * a1);          \
        float r23 = __builtin_amdgcn_rcpf(a2 * a3);          \
        float t01 = nw2 * r01, t23 = nw2 * r23;              \
        acc[0][jm] = fmaf(t01, a1, acc[0][jm]);              \
        acc[1][jm] = fmaf(t01, a0, acc[1][jm]);              \
        acc[2][jm] = fmaf(t23, a3, acc[2][jm]);              \
        acc[3][jm] = fmaf(t23, a2, acc[3][jm]);              \
    }

__global__ __launch_bounds__(512) void scores_kernel(
    const float* __restrict__ EqT, const float* __restrict__ EkT,
    const float* __restrict__ Wv, float* __restrict__ P,
    float* __restrict__ Spart)
{
    const int idx = blockIdx.x;
    const int b   = idx & 3;
    const int mt  = (idx >> 2) & 7;
    const int nt  = idx >> 5;          // 0..7
    const int m0  = mt * 64, n0 = nt * 64;
    const int t    = threadIdx.x;
    const int lane = t & 63;
    const int wid  = t >> 6;
    const int g    = wid >> 2;               // h-group: waves 0-3 -> 0, 4-7 -> 1
    const int tg   = (wid & 3) * 64 + lane;  // 0..255 within group
    const int tx   = tg & 15;   // m quad (4 each)
    const int ty   = tg >> 4;   // n quad (4 each)

    __shared__ float sQ[2][2][16][68];   // [g][buf][hh][nn] 16h x 64n (+pad)
    __shared__ float sK[2][2][16][68];   // [g][buf][hh][mm]

    const int rs_ = tg >> 4, cs_ = tg & 15;   // stage: 16 h rows x 16 grps(4)

    const float* qbase = &EqT[(size_t)(b * HDIM + g * 128) * NQL + n0];
    const float* kbase = &EkT[(size_t)(b * HDIM + g * 128) * ML + m0];

    // preload chunk 0 (16 h rows) into staging regs
    float4 qv = *(const float4*)(qbase + (size_t)rs_ * NQL + cs_ * 4);
    float4 kv = *(const float4*)(kbase + (size_t)rs_ * ML + cs_ * 4);

    float acc[4][4] = {};
    int cur = 0;

    for (int c = 0; c < 8; ++c) {   // 8 chunks of 16 hh (this group's 128 h)
        *(float4*)&sQ[g][cur][rs_][cs_ * 4] = qv;
        *(float4*)&sK[g][cur][rs_][cs_ * 4] = kv;
        __syncthreads();
        if (c < 7) {   // prefetch next chunk; latency hides under compute
            qv = *(const float4*)(qbase + (size_t)((c + 1) * 16 + rs_) * NQL + cs_ * 4);
            kv = *(const float4*)(kbase + (size_t)((c + 1) * 16 + rs_) * ML + cs_ * 4);
        }
        const float* wvp = Wv + g * 128 + c * 16;   // uniform -> scalar loads
        #pragma unroll
        for (int hh = 0; hh < 16; ++hh) {
            float4 q4 = *(const float4*)&sQ[g][cur][hh][ty * 4];
            float4 k4 = *(const float4*)&sK[g][cur][hh][tx * 4];
            const float nw2 = -2.0f * wvp[hh];
            SC_M(0, k4.x) SC_M(1, k4.y) SC_M(2, k4.z) SC_M(3, k4.w)
        }
        cur ^= 1;
    }

    // combine the two h-halves through LDS (reuse sQ region, 16 KB needed)
    __syncthreads();
    float* sred = &sQ[0][0][0][0];
    if (g == 1) {
        #pragma unroll
        for (int i = 0; i < 4; ++i)
            #pragma unroll
            for (int j = 0; j < 4; ++j)
                sred[(i * 4 + j) * 256 + tg] = acc[i][j];   // b32 stride-4, clean
    }
    __syncthreads();
    if (g == 0) {
        float swv = 0.f;   // sum of all Wv: uniform -> scalar math
        #pragma unroll 8
        for (int i = 0; i < HDIM; i += 4) {
            float4 w = *(const float4*)(Wv + i);
            swv += (w.x + w.y) + (w.z + w.w);
        }
        float rsum[4];
        #pragma unroll
        for (int i = 0; i < 4; ++i) {
            float4 p;
            p.x = __builtin_amdgcn_exp2f((swv + acc[i][0] + sred[(i * 4 + 0) * 256 + tg]) * LOG2E);
            p.y = __builtin_amdgcn_exp2f((swv + acc[i][1] + sred[(i * 4 + 1) * 256 + tg]) * LOG2E);
            p.z = __builtin_amdgcn_exp2f((swv + acc[i][2] + sred[(i * 4 + 2) * 256 + tg]) * LOG2E);
            p.w = __builtin_amdgcn_exp2f((swv + acc[i][3] + sred[(i * 4 + 3) * 256 + tg]) * LOG2E);
            *(float4*)&P[(size_t)(b * NQL + n0 + ty * 4 + i) * ML + m0 + tx * 4] = p;
            rsum[i] = (p.x + p.y) + (p.z + p.w);
        }
        #pragma unroll
        for (int off = 1; off < 16; off <<= 1) {  // reduce over the 16 tx lanes
            #pragma unroll
            for (int i = 0; i < 4; ++i) rsum[i] += __shfl_xor(rsum[i], off);
        }
        if (tx == 0) {
            #pragma unroll
            for (int i = 0; i < 4; ++i)
                Spart[(size_t)(mt * NB + b) * NQL + n0 + ty * 4 + i] = rsum[i];
        }
    }
}

// ---------------------------------------------------------------------------
// Kernel 3: out[b][n][v] = (sum_m P[b][n][m] * V[b][m][v]) / rowsum[b][n]
// NO LDS for operands; double-buffered register pipeline, fenced.
// 16n x 64v tile, m-split 4 across the block's 4 waves (128 m each),
// 256 thr, 4n x 4v per thread. Chunk = 4 m (4 P b128 + 4 V b128, 64 fma).
// LDS only for the 3->1 epilogue reduce. grid 512 (1D), 2 blocks/CU.
// ---------------------------------------------------------------------------
#define AV_ONE(PSb, VSb, i, r, comp)                                 \
    acc[i][0] = fmaf(PSb[i].comp, VSb[r].x, acc[i][0]);              \
    acc[i][1] = fmaf(PSb[i].comp, VSb[r].y, acc[i][1]);              \
    acc[i][2] = fmaf(PSb[i].comp, VSb[r].z, acc[i][2]);              \
    acc[i][3] = fmaf(PSb[i].comp, VSb[r].w, acc[i][3]);
#define AV_RR(PSb, VSb, r, comp)                                     \
    AV_ONE(PSb, VSb, 0, r, comp) AV_ONE(PSb, VSb, 1, r, comp)        \
    AV_ONE(PSb, VSb, 2, r, comp) AV_ONE(PSb, VSb, 3, r, comp)
#define AV_COMP(PSb, VSb)                                            \
    AV_RR(PSb, VSb, 0, x) AV_RR(PSb, VSb, 1, y)                      \
    AV_RR(PSb, VSb, 2, z) AV_RR(PSb, VSb, 3, w)

#define AV_LOAD(PSb, VSb, c)                                              \
    {                                                                     \
        const int mm_ = (c) * 4;                                          \
        _Pragma("unroll")                                                 \
        for (int r_ = 0; r_ < 4; ++r_) {                                  \
            PSb[r_] = *(const float4*)(pbase + (size_t)r_ * ML + mm_);    \
            VSb[r_] = *(const float4*)(vbase + (size_t)(mm_ + r_) * DDIM);\
        }                                                                 \
    }

__global__ __launch_bounds__(256) void av_kernel(
    const float* __restrict__ P, const float* __restrict__ Spart,
    const float* __restrict__ V, float* __restrict__ O)
{
    const int idx = blockIdx.x;
    const int b   = idx & 3;
    const int vt  = (idx >> 2) & 3;
    const int nt  = idx >> 4;          // 0..31
    const int v0  = vt * 64, n0 = nt * 16;
    const int t    = threadIdx.x;
    const int lane = t & 63;
    const int wid  = t >> 6;    // m-quarter selector (4 waves)
    const int tx   = lane & 15; // v group (4 each)
    const int tn   = lane >> 4; // n group (4 rows each)

    __shared__ float sInv[16];
    __shared__ float sRed[3][16][64];   // 12 KB epilogue reduce

    if (t < 16) {   // softmax denominators from the 8 scores partials
        float s = 0.f;
        #pragma unroll
        for (int mt = 0; mt < 8; ++mt)
            s += Spart[(size_t)(mt * NB + b) * NQL + n0 + t];
        sInv[t] = 1.0f / s;
    }

    const float* pbase = &P[(size_t)(b * NQL + n0 + tn * 4) * ML + wid * 128];
    const float* vbase = &V[(size_t)(b * ML + wid * 128) * DDIM + v0 + tx * 4];

    float4 PA[4], VA[4];     // buffer A: [row]; P row = n, V row = m
    float4 PB[4], VB[4];     // buffer B
    float acc[4][4] = {};

    // 32 chunks of 4 m. Double-buffered, fenced.
    AV_LOAD(PA, VA, 0)
    SB();
    for (int v = 0; v < 15; ++v) {
        AV_LOAD(PB, VB, 2 * v + 1)
        SB();
        AV_COMP(PA, VA)
        SB();
        AV_LOAD(PA, VA, 2 * v + 2)
        SB();
        AV_COMP(PB, VB)
        SB();
    }
    AV_LOAD(PB, VB, 31)
    SB();
    AV_COMP(PA, VA)          // chunk 30
    SB();
    AV_COMP(PB, VB)          // chunk 31

    __syncthreads();
    if (wid != 0) {
        #pragma unroll
        for (int i = 0; i < 4; ++i) {
            float4 r = {acc[i][0], acc[i][1], acc[i][2], acc[i][3]};
            *(float4*)&sRed[wid - 1][tn * 4 + i][tx * 4] = r;
        }
    }
    __syncthreads();
    if (wid == 0) {
        #pragma unroll
        for (int i = 0; i < 4; ++i) {
            float4 r1 = *(const float4*)&sRed[0][tn * 4 + i][tx * 4];
            float4 r2 = *(const float4*)&sRed[1][tn * 4 + i][tx * 4];
            float4 r3 = *(const float4*)&sRed[2][tn * 4 + i][tx * 4];
            const float inv = sInv[tn * 4 + i];
            float4 o;
            o.x = (acc[i][0] + r1.x + r2.x + r3.x) * inv;
            o.y = (acc[i][1] + r1.y + r2.y + r3.y) * inv;
            o.z = (acc[i][2] + r1.z + r2.z + r3.z) * inv;
            o.w = (acc[i][3] + r1.w + r2.w + r3.w) * inv;
            *(float4*)&O[(size_t)(b * NQL + n0 + tn * 4 + i) * DDIM + v0 + tx * 4] = o;
        }
    }
}

// ---------------------------------------------------------------------------
extern "C" void kernel_launch(void* const* d_in, const int* in_sizes, int n_in,
                              void* d_out, int out_size, void* d_ws, size_t ws_size,
                              hipStream_t stream)
{
    const float* query = (const float*)d_in[0]; // (4,512,256)
    const float* key   = (const float*)d_in[1]; // (4,512,256)
    const float* value = (const float*)d_in[2]; // (4,512,256)
    const float* Wq    = (const float*)d_in[3]; // (256,256)
    const float* Wk    = (const float*)d_in[4]; // (256,256)
    const float* Wv    = (const float*)d_in[5]; // (256,)
    float* out = (float*)d_out;                 // (4,512,256)

    // workspace layout (fp32): EqT 2MB | EkT 2MB | P 4MB | Spart 64KB
    float* EqT   = (float*)d_ws;                      // [4][256][512]
    float* EkT   = EqT + (size_t)NB * HDIM * NQL;     // [4][256][512]
    float* P     = EkT + (size_t)NB * HDIM * ML;      // [4][512][512] (= exp(S))
    float* Spart = P + (size_t)NB * NQL * ML;         // [8][4][512] partial row sums

    proj_kernel<<<dim3(256), 256, 0, stream>>>(query, key, Wq, Wk, EqT, EkT);
    scores_kernel<<<dim3(256), 512, 0, stream>>>(EqT, EkT, Wv, P, Spart);
    av_kernel<<<dim3(512), 256, 0, stream>>>(P, Spart, value, out);
}